// Round 6
// baseline (44.145 us; speedup 1.0000x reference)
//
#include <hip/hip_runtime.h>
#include <hip/hip_bf16.h>
#include <math.h>

typedef __attribute__((ext_vector_type(8)))  short bf16x8;
typedef __attribute__((ext_vector_type(16))) float f32x16;
typedef unsigned int u32;

#define KAPPA (1.0f/61.0f)
#define NBLK 1024          // (32768/64 sample-groups) x 2 p-halves

__device__ __forceinline__ unsigned short f2bf(float f) {
    u32 x = __float_as_uint(f);
    x += 0x7fffu + ((x >> 16) & 1u);               // RNE
    return (unsigned short)(x >> 16);
}
__device__ __forceinline__ float fast_rcp(float v) {
#if __has_builtin(__builtin_amdgcn_rcpf)
    return __builtin_amdgcn_rcpf(v);
#else
    return 1.0f / v;
#endif
}
__device__ __forceinline__ u32 pack_bf16(float lo, float hi) {
    __hip_bfloat162 p = __float22bfloat162_rn(make_float2(lo, hi));  // v_cvt_pk path
    return *reinterpret_cast<u32*>(&p);
}

// ---------------------------------------------------------------------------
// Kernel 1: precompute MFMA operand fragments (all sample-independent).
//  V  frags [16384]: f=(kkg*8+ptile)*64+lane -> A-frag of V^T:
//       row p = ptile*32+(lane&31), k h = kkg*16+(lane>>5)*8+i
//       V[h][p] = W1[l][h]*W2[h][c], p=l*35+c (pad 245->256)
//  Wt frags [1024]:  f=htile*64+lane -> A-frag of [W1^T | b1]:
//       row h = htile*32+(lane&31); lo half k=0..6 -> W1[k][h], k=7 -> b1[h]; hi 0
// ---------------------------------------------------------------------------
__global__ void build_v(const float* __restrict__ W1, const float* __restrict__ W2,
                        const float* __restrict__ b1,
                        bf16x8* __restrict__ V, bf16x8* __restrict__ Wt) {
    int t = blockIdx.x * blockDim.x + threadIdx.x;
    if (t < 16384) {
        int lane = t & 63, ptile = (t >> 6) & 7, kkg = t >> 9;
        int p  = ptile * 32 + (lane & 31);
        int hb = kkg * 16 + (lane >> 5) * 8;
        bool valid = (p < 245);
        int l7 = valid ? p / 35 : 0;
        int c  = valid ? p - l7 * 35 : 0;
        bf16x8 v;
#pragma unroll
        for (int i = 0; i < 8; ++i) {
            int h = hb + i;
            v[i] = valid ? (short)f2bf(W1[l7 * 512 + h] * W2[h * 35 + c]) : (short)0;
        }
        V[t] = v;
    } else if (t < 16384 + 1024) {
        int f = t - 16384;
        int lane = f & 63, htile = f >> 6;
        int h = htile * 32 + (lane & 31);
        bf16x8 v;
#pragma unroll
        for (int i = 0; i < 8; ++i) v[i] = 0;
        if (lane < 32) {
#pragma unroll
            for (int l = 0; l < 7; ++l) v[l] = (short)f2bf(W1[l * 512 + h]);
            v[7] = (short)f2bf(b1[h]);
        }
        Wt[f] = v;
    }
}

// ---------------------------------------------------------------------------
// Kernel 2: main. 1024 blocks x 256 threads (4 waves); block = 64 samples x
// 128 p (one p-half). Wave w: phase A computes pre-tile (ht=w>>1, st=w&1);
// phase B contracts ptiles {2*(w>>1), 2*(w>>1)+1} of this p-half against
// G frags of st=w&1. acc = 32 VGPR; LDS ~17 KB; launch_bounds(256,4) ->
// 4 independently-barriered blocks/CU so phases anti-phase across blocks.
// Per-sample partial SSQ (over this p-half) -> global; finalize does sqrt.
// ---------------------------------------------------------------------------
__global__ __launch_bounds__(256, 4)
void torsion_main(const float* __restrict__ x,
                  const bf16x8* __restrict__ V, const bf16x8* __restrict__ Wt,
                  float* __restrict__ partials) {
    __shared__ __align__(16) u32 Gb[2][8][64 * 4];   // [buf][ks*2+st][...] = 16 KB
    __shared__ float red[2][64];

    const int tid  = threadIdx.x;
    const int lane = tid & 63;
    const int w    = tid >> 6;
    const int st   = w & 1;      // sample tile (pre + consume)
    const int hp   = w >> 1;     // h-subtile in phase A; p-pair in phase B
    const int sblk = blockIdx.x >> 1;
    const int ph   = blockIdx.x & 1;   // p-half (ptiles ph*4 .. ph*4+3)

    // x B-frag: col = sample, lo half k=0..6 -> x, k=7 -> 1.0; hi half 0
    bf16x8 xf;
#pragma unroll
    for (int i = 0; i < 8; ++i) xf[i] = 0;
    if (lane < 32) {
        const float* xp = x + ((size_t)sblk * 64 + st * 32 + lane) * 7;
#pragma unroll
        for (int l = 0; l < 7; ++l) xf[l] = (short)f2bf(xp[l]);
        xf[7] = (short)f2bf(1.0f);
    }

    f32x16 acc[2];
#pragma unroll
    for (int pt = 0; pt < 2; ++pt)
#pragma unroll
        for (int e = 0; e < 16; ++e) acc[pt][e] = 0.0f;

    // pre^T subtile (32 h x 32 samples) for chunk c -> 8 packed g dwords
    auto pre_pack = [&](int c, u32 d[8]) {
        bf16x8 wf = Wt[(c * 2 + hp) * 64 + lane];
        f32x16 p;
#pragma unroll
        for (int e = 0; e < 16; ++e) p[e] = 0.0f;
        p = __builtin_amdgcn_mfma_f32_32x32x16_bf16(wf, xf, p, 0, 0, 0);
#pragma unroll
        for (int j = 0; j < 8; ++j) {
            float t0 = __expf(-2.0f * fabsf(p[2 * j]));
            float r0 = fast_rcp(1.0f + t0);
            float g0 = 4.0f * t0 * r0 * r0;
            float t1 = __expf(-2.0f * fabsf(p[2 * j + 1]));
            float r1 = fast_rcp(1.0f + t1);
            float g1 = 4.0f * t1 * r1 * r1;
            d[j] = pack_bf16(g0, g1);
        }
    };
    // lane's packed dwords -> G^T B-frags via addressing (free transpose)
    auto store_g = [&](int buf, const u32 d[8]) {
        const int f0  = 4 * hp + st;             // kstep 2*hp
        const int f1  = f0 + 2;                  // kstep 2*hp+1
        const int col = lane & 31;
        const int hw2 = (lane >> 5) << 1;        // 0 or 2 dwords
        *reinterpret_cast<uint2*>(&Gb[buf][f0][(col     ) * 4 + hw2]) = make_uint2(d[0], d[1]);
        *reinterpret_cast<uint2*>(&Gb[buf][f0][(col + 32) * 4 + hw2]) = make_uint2(d[2], d[3]);
        *reinterpret_cast<uint2*>(&Gb[buf][f1][(col     ) * 4 + hw2]) = make_uint2(d[4], d[5]);
        *reinterpret_cast<uint2*>(&Gb[buf][f1][(col + 32) * 4 + hw2]) = make_uint2(d[6], d[7]);
    };

    {
        u32 d0[8];
        pre_pack(0, d0);
        store_g(0, d0);
    }
    __syncthreads();

    for (int c = 0; c < 8; ++c) {
        const int buf = c & 1;
        u32 dn[8];
        if (c < 7) pre_pack(c + 1, dn);
        __builtin_amdgcn_s_setprio(1);
#pragma unroll
        for (int ks = 0; ks < 4; ++ks) {
            bf16x8 g = *reinterpret_cast<const bf16x8*>(&Gb[buf][ks * 2 + st][lane * 4]);
            const int fb = ((c * 4 + ks) * 8 + ph * 4 + 2 * hp) * 64 + lane;
            bf16x8 va = V[fb];
            bf16x8 vb = V[fb + 64];
            acc[0] = __builtin_amdgcn_mfma_f32_32x32x16_bf16(va, g, acc[0], 0, 0, 0);
            acc[1] = __builtin_amdgcn_mfma_f32_32x32x16_bf16(vb, g, acc[1], 0, 0, 0);
        }
        __builtin_amdgcn_s_setprio(0);
        if (c < 7) store_g(buf ^ 1, dn);
        __syncthreads();
    }

    // ---- epilogue: partial SSQ over this p-half, per sample ----
    // D[p][sample]: col = sample; lane & lane^32 hold complementary p-slices.
    {
        float s = 0.0f;
#pragma unroll
        for (int pt = 0; pt < 2; ++pt)
#pragma unroll
            for (int e = 0; e < 16; ++e) s += acc[pt][e] * acc[pt][e];
        s += __shfl_xor(s, 32);
        if (lane < 32) red[hp][st * 32 + lane] = s;
    }
    __syncthreads();

    if (tid < 64) {
        partials[(size_t)ph * 32768 + sblk * 64 + tid] = red[0][tid] + red[1][tid];
    }
}

// ---------------------------------------------------------------------------
// Kernel 3: finalize — per-sample sqrt + deterministic mean over 32768.
// ---------------------------------------------------------------------------
__global__ __launch_bounds__(1024)
void finalize_k(const float* __restrict__ partials, float* __restrict__ out) {
    __shared__ float sl[1024], sn[1024];
    const int tid = threadIdx.x;
    float a = 0.0f, b = 0.0f;
    for (int s = tid; s < 32768; s += 1024) {
        float q = 6.0f * (partials[s] + partials[32768 + s]);
        float n = sqrtf(q + 1e-10f);
        float d = n - KAPPA;
        a += d * d;
        b += n;
    }
    sl[tid] = a; sn[tid] = b;
    __syncthreads();
    for (int st = 512; st > 0; st >>= 1) {
        if (tid < st) { sl[tid] += sl[tid + st]; sn[tid] += sn[tid + st]; }
        __syncthreads();
    }
    if (tid == 0) {
        out[0] = sl[0] / 32768.0f;
        out[1] = sn[0] / 32768.0f;
    }
}

// ---------------------------------------------------------------------------
extern "C" void kernel_launch(void* const* d_in, const int* in_sizes, int n_in,
                              void* d_out, int out_size, void* d_ws, size_t ws_size,
                              hipStream_t stream) {
    const float* x  = (const float*)d_in[0];
    const float* W1 = (const float*)d_in[1];
    const float* b1 = (const float*)d_in[2];
    const float* W2 = (const float*)d_in[3];
    // b2 (d_in[4]) unused: the Jacobian kills the bias.

    bf16x8* V        = (bf16x8*)d_ws;          // 16384 frags * 16 B = 256 KB
    bf16x8* Wt       = V + 16384;              // 1024 frags * 16 B = 16 KB
    float*  partials = (float*)(Wt + 1024);    // 2 * 32768 floats = 256 KB

    build_v<<<68, 256, 0, stream>>>(W1, W2, b1, V, Wt);
    torsion_main<<<NBLK, 256, 0, stream>>>(x, V, Wt, partials);
    finalize_k<<<1, 1024, 0, stream>>>(partials, (float*)d_out);
}

// Round 7
// 25.706 us; speedup vs baseline: 1.7173x; 1.7173x over previous
//
#include <hip/hip_runtime.h>
#include <hip/hip_bf16.h>
#include <math.h>

typedef __attribute__((ext_vector_type(8)))  short bf16x8;
typedef __attribute__((ext_vector_type(16))) float f32x16;
typedef unsigned int u32;

#define KAPPA (1.0f/61.0f)
#define NBLK 512           // 32768 rows / 64 rows-per-block

__device__ __forceinline__ unsigned short f2bf(float f) {
    u32 x = __float_as_uint(f);
    x += 0x7fffu + ((x >> 16) & 1u);               // RNE
    return (unsigned short)(x >> 16);
}
__device__ __forceinline__ float fast_rcp(float v) {
#if __has_builtin(__builtin_amdgcn_rcpf)
    return __builtin_amdgcn_rcpf(v);
#else
    return 1.0f / v;
#endif
}
__device__ __forceinline__ u32 pack_bf16(float lo, float hi) {
    __hip_bfloat162 p = __float22bfloat162_rn(make_float2(lo, hi));  // v_cvt_pk path
    return *reinterpret_cast<u32*>(&p);
}

// ---------------------------------------------------------------------------
// Kernel 1: precompute MFMA operand fragments (all sample-independent).
//  V  frags [16384]: f=(kkg*8+ptile)*64+lane -> A-frag of V^T:
//       row p = ptile*32+(lane&31), k h = kkg*16+(lane>>5)*8+i
//       V[h][p] = W1[l][h]*W2[h][c], p=l*35+c (pad 245->256)
//  Wt frags [1024]:  f=htile*64+lane -> A-frag of [W1^T | b1]:
//       row h = htile*32+(lane&31); lo half k=0..6 -> W1[k][h], k=7 -> b1[h]; hi 0
// ---------------------------------------------------------------------------
__global__ void build_v(const float* __restrict__ W1, const float* __restrict__ W2,
                        const float* __restrict__ b1,
                        bf16x8* __restrict__ V, bf16x8* __restrict__ Wt) {
    int t = blockIdx.x * blockDim.x + threadIdx.x;
    if (t < 16384) {
        int lane = t & 63, ptile = (t >> 6) & 7, kkg = t >> 9;
        int p  = ptile * 32 + (lane & 31);
        int hb = kkg * 16 + (lane >> 5) * 8;
        bool valid = (p < 245);
        int l7 = valid ? p / 35 : 0;
        int c  = valid ? p - l7 * 35 : 0;
        bf16x8 v;
#pragma unroll
        for (int i = 0; i < 8; ++i) {
            int h = hb + i;
            v[i] = valid ? (short)f2bf(W1[l7 * 512 + h] * W2[h * 35 + c]) : (short)0;
        }
        V[t] = v;
    } else if (t < 16384 + 1024) {
        int f = t - 16384;
        int lane = f & 63, htile = f >> 6;
        int h = htile * 32 + (lane & 31);
        bf16x8 v;
#pragma unroll
        for (int i = 0; i < 8; ++i) v[i] = 0;
        if (lane < 32) {
#pragma unroll
            for (int l = 0; l < 7; ++l) v[l] = (short)f2bf(W1[l * 512 + h]);
            v[7] = (short)f2bf(b1[h]);
        }
        Wt[f] = v;
    }
}

// ---------------------------------------------------------------------------
// Kernel 2: main (r4 structure + batched V register prefetch).
// 512 blocks x 256 threads (4 waves); block = 64 samples x 256 p; g computed
// once per sample. Wave w: phase A pre-tile (ht=w>>1, rt=w&1); phase B
// ptiles {2w, 2w+1} x both sample tiles (acc[2][2] = 64 VGPR).
// Chunk = 64 h. NEW order per chunk: (1) issue all 8 V-frag loads of this
// chunk into vreg (32 VGPR, 8 loads in flight), (2) pre_pack(c+1) trans chain
// hides V L2 latency, (3) 16-MFMA cluster consumes vreg, (4) store_g, barrier.
// ---------------------------------------------------------------------------
__global__ __launch_bounds__(256, 3)
void torsion_main(const float* __restrict__ x,
                  const bf16x8* __restrict__ V, const bf16x8* __restrict__ Wt,
                  float* __restrict__ partials) {
    __shared__ __align__(16) u32 Gb[2][8][64 * 4];   // [buf][ks*2+rt][lane dwords] = 16KB
    __shared__ float red[4][2][32];

    const int tid  = threadIdx.x;
    const int lane = tid & 63;
    const int w    = tid >> 6;
    const int blk  = blockIdx.x;
    const int rt   = w & 1;      // sample tile this wave's pre covers
    const int ht   = w >> 1;     // h-subtile (0..1) within chunk

    // x B-frag (once): col = sample, lo half k=0..6 -> x, k=7 -> 1.0; hi half 0
    bf16x8 xf;
#pragma unroll
    for (int i = 0; i < 8; ++i) xf[i] = 0;
    if (lane < 32) {
        const float* xp = x + ((size_t)blk * 64 + rt * 32 + lane) * 7;
#pragma unroll
        for (int l = 0; l < 7; ++l) xf[l] = (short)f2bf(xp[l]);
        xf[7] = (short)f2bf(1.0f);
    }

    f32x16 acc[2][2];
#pragma unroll
    for (int pt = 0; pt < 2; ++pt)
#pragma unroll
        for (int r2 = 0; r2 < 2; ++r2)
#pragma unroll
            for (int e = 0; e < 16; ++e) acc[pt][r2][e] = 0.0f;

    // pre^T tile for chunk c -> 8 packed dwords of g (bf16 pairs)
    auto pre_pack = [&](int c, u32 d[8]) {
        bf16x8 wf = Wt[(c * 2 + ht) * 64 + lane];
        f32x16 p;
#pragma unroll
        for (int e = 0; e < 16; ++e) p[e] = 0.0f;
        p = __builtin_amdgcn_mfma_f32_32x32x16_bf16(wf, xf, p, 0, 0, 0);
#pragma unroll
        for (int j = 0; j < 8; ++j) {
            float t0 = __expf(-2.0f * fabsf(p[2 * j]));
            float r0 = fast_rcp(1.0f + t0);
            float g0 = 4.0f * t0 * r0 * r0;
            float t1 = __expf(-2.0f * fabsf(p[2 * j + 1]));
            float r1 = fast_rcp(1.0f + t1);
            float g1 = 4.0f * t1 * r1 * r1;
            d[j] = pack_bf16(g0, g1);
        }
    };
    // store: lane's dwords -> G^T B-frags via addressing (free transpose)
    auto store_g = [&](int buf, const u32 d[8]) {
        const int f0  = 4 * ht + rt;             // kstep 2*ht
        const int f1  = f0 + 2;                  // kstep 2*ht+1
        const int col = lane & 31;
        const int hw2 = (lane >> 5) << 1;        // 0 or 2 dwords
        *reinterpret_cast<uint2*>(&Gb[buf][f0][(col     ) * 4 + hw2]) = make_uint2(d[0], d[1]);
        *reinterpret_cast<uint2*>(&Gb[buf][f0][(col + 32) * 4 + hw2]) = make_uint2(d[2], d[3]);
        *reinterpret_cast<uint2*>(&Gb[buf][f1][(col     ) * 4 + hw2]) = make_uint2(d[4], d[5]);
        *reinterpret_cast<uint2*>(&Gb[buf][f1][(col + 32) * 4 + hw2]) = make_uint2(d[6], d[7]);
    };

    {
        u32 d0[8];
        pre_pack(0, d0);
        store_g(0, d0);
    }
    __syncthreads();

    for (int c = 0; c < 8; ++c) {
        const int buf = c & 1;

        // (1) issue ALL this chunk's V loads back-to-back (8 dwordx4 in flight)
        bf16x8 vreg[8];
#pragma unroll
        for (int ks = 0; ks < 4; ++ks) {
            const int fb = ((c * 4 + ks) * 8 + 2 * w) * 64 + lane;
            vreg[2 * ks]     = V[fb];
            vreg[2 * ks + 1] = V[fb + 64];
        }

        // (2) next chunk's pre: trans chain hides V latency
        u32 dn[8];
        if (c < 7) pre_pack(c + 1, dn);

        // (3) MFMA cluster
        __builtin_amdgcn_s_setprio(1);
#pragma unroll
        for (int ks = 0; ks < 4; ++ks) {
            bf16x8 g0 = *reinterpret_cast<const bf16x8*>(&Gb[buf][ks * 2 + 0][lane * 4]);
            bf16x8 g1 = *reinterpret_cast<const bf16x8*>(&Gb[buf][ks * 2 + 1][lane * 4]);
            acc[0][0] = __builtin_amdgcn_mfma_f32_32x32x16_bf16(vreg[2 * ks],     g0, acc[0][0], 0, 0, 0);
            acc[0][1] = __builtin_amdgcn_mfma_f32_32x32x16_bf16(vreg[2 * ks],     g1, acc[0][1], 0, 0, 0);
            acc[1][0] = __builtin_amdgcn_mfma_f32_32x32x16_bf16(vreg[2 * ks + 1], g0, acc[1][0], 0, 0, 0);
            acc[1][1] = __builtin_amdgcn_mfma_f32_32x32x16_bf16(vreg[2 * ks + 1], g1, acc[1][1], 0, 0, 0);
        }
        __builtin_amdgcn_s_setprio(0);

        // (4) publish next chunk's G, then barrier
        if (c < 7) store_g(buf ^ 1, dn);
        __syncthreads();
    }

    // ---- epilogue: D[p][sample]: col = sample; lane & lane^32 share a sample.
#pragma unroll
    for (int r2 = 0; r2 < 2; ++r2) {
        float s = 0.0f;
#pragma unroll
        for (int pt = 0; pt < 2; ++pt)
#pragma unroll
            for (int e = 0; e < 16; ++e) s += acc[pt][r2][e] * acc[pt][r2][e];
        s += __shfl_xor(s, 32);
        if (lane < 32) red[w][r2][lane] = s;
    }
    __syncthreads();

    if (tid < 64) {
        const int li = tid & 31, rr = tid >> 5;
        float q = 6.0f * (red[0][rr][li] + red[1][rr][li] + red[2][rr][li] + red[3][rr][li]);
        float n = sqrtf(q + 1e-10f);
        float d = n - KAPPA;
        float a = d * d, b = n;
#pragma unroll
        for (int m = 1; m <= 32; m <<= 1) {
            a += __shfl_xor(a, m);
            b += __shfl_xor(b, m);
        }
        if (tid == 0) {
            partials[blk]        = a;
            partials[NBLK + blk] = b;
        }
    }
}

// ---------------------------------------------------------------------------
// Kernel 3: finalize — deterministic sum of 512 per-block partials.
// ---------------------------------------------------------------------------
__global__ void finalize_k(const float* __restrict__ partials, float* __restrict__ out) {
    __shared__ float sl[256], sn[256];
    int tid = threadIdx.x;
    sl[tid] = partials[tid] + partials[tid + 256];
    sn[tid] = partials[NBLK + tid] + partials[NBLK + tid + 256];
    __syncthreads();
    for (int st = 128; st > 0; st >>= 1) {
        if (tid < st) { sl[tid] += sl[tid + st]; sn[tid] += sn[tid + st]; }
        __syncthreads();
    }
    if (tid == 0) {
        out[0] = sl[0] / 32768.0f;
        out[1] = sn[0] / 32768.0f;
    }
}

// ---------------------------------------------------------------------------
extern "C" void kernel_launch(void* const* d_in, const int* in_sizes, int n_in,
                              void* d_out, int out_size, void* d_ws, size_t ws_size,
                              hipStream_t stream) {
    const float* x  = (const float*)d_in[0];
    const float* W1 = (const float*)d_in[1];
    const float* b1 = (const float*)d_in[2];
    const float* W2 = (const float*)d_in[3];
    // b2 (d_in[4]) unused: the Jacobian kills the bias.

    bf16x8* V        = (bf16x8*)d_ws;          // 16384 frags * 16 B = 256 KB
    bf16x8* Wt       = V + 16384;              // 1024 frags * 16 B = 16 KB
    float*  partials = (float*)(Wt + 1024);    // 1024 floats

    build_v<<<68, 256, 0, stream>>>(W1, W2, b1, V, Wt);
    torsion_main<<<NBLK, 256, 0, stream>>>(x, V, Wt, partials);
    finalize_k<<<1, 256, 0, stream>>>(partials, (float*)d_out);
}